// Round 1
// baseline (355.590 us; speedup 1.0000x reference)
//
#include <hip/hip_runtime.h>
#include <hip/hip_bf16.h>
#include <math.h>

// Problem constants
#define B_   2
#define L_   2048
#define HID_ 512
#define NH_  8
#define HD_  64
#define SK_  40
#define NTOP_ 40
#define NBH_ (B_ * NH_)        // 16
#define NROW_ (B_ * L_)        // 4096
#define CHUNK_ 64
#define NCH_ (L_ / CHUNK_)     // 32

// ---------------------------------------------------------------------------
// Kernel 1: fused QKV projection.  C[i,j] = sum_k A[i,k] * W[j,k] + bias[j]
// Output layout: (B, NH, L, HD)  out[((b*NH+h)*L + l)*HD + d], j = h*64+d
// 64x64 tile, BK=32, 256 threads, 4x4 per thread. k-major LDS, pad 68.
// ---------------------------------------------------------------------------
__global__ __launch_bounds__(256) void proj_kernel(
    const float* __restrict__ A,
    const float* __restrict__ Wq, const float* __restrict__ bq,
    const float* __restrict__ Wk, const float* __restrict__ bk,
    const float* __restrict__ Wv, const float* __restrict__ bv,
    float* __restrict__ qo, float* __restrict__ ko, float* __restrict__ vo)
{
    const float* W; const float* bias; float* out;
    if (blockIdx.z == 0)      { W = Wq; bias = bq; out = qo; }
    else if (blockIdx.z == 1) { W = Wk; bias = bk; out = ko; }
    else                      { W = Wv; bias = bv; out = vo; }

    __shared__ __align__(16) float As[32][68];
    __shared__ __align__(16) float Bs[32][68];

    const int t   = threadIdx.x;
    const int lr  = t >> 3;            // 0..31
    const int lc  = (t & 7) << 2;      // 0,4,...,28
    const int row0 = blockIdx.x * 64;
    const int h    = blockIdx.y;       // head == 64-col tile
    const int col0 = h * 64;
    const int ty = t >> 4, tx = t & 15;

    float acc[4][4] = {};

    for (int k0 = 0; k0 < HID_; k0 += 32) {
        #pragma unroll
        for (int p = 0; p < 2; ++p) {
            int r = lr + p * 32;
            float4 av = *reinterpret_cast<const float4*>(&A[(row0 + r) * HID_ + k0 + lc]);
            As[lc + 0][r] = av.x; As[lc + 1][r] = av.y;
            As[lc + 2][r] = av.z; As[lc + 3][r] = av.w;
            float4 wv = *reinterpret_cast<const float4*>(&W[(col0 + r) * HID_ + k0 + lc]);
            Bs[lc + 0][r] = wv.x; Bs[lc + 1][r] = wv.y;
            Bs[lc + 2][r] = wv.z; Bs[lc + 3][r] = wv.w;
        }
        __syncthreads();
        #pragma unroll
        for (int kk = 0; kk < 32; ++kk) {
            const float4 av = *reinterpret_cast<const float4*>(&As[kk][ty << 2]);
            const float4 bv = *reinterpret_cast<const float4*>(&Bs[kk][tx << 2]);
            acc[0][0] = fmaf(av.x, bv.x, acc[0][0]);
            acc[0][1] = fmaf(av.x, bv.y, acc[0][1]);
            acc[0][2] = fmaf(av.x, bv.z, acc[0][2]);
            acc[0][3] = fmaf(av.x, bv.w, acc[0][3]);
            acc[1][0] = fmaf(av.y, bv.x, acc[1][0]);
            acc[1][1] = fmaf(av.y, bv.y, acc[1][1]);
            acc[1][2] = fmaf(av.y, bv.z, acc[1][2]);
            acc[1][3] = fmaf(av.y, bv.w, acc[1][3]);
            acc[2][0] = fmaf(av.z, bv.x, acc[2][0]);
            acc[2][1] = fmaf(av.z, bv.y, acc[2][1]);
            acc[2][2] = fmaf(av.z, bv.z, acc[2][2]);
            acc[2][3] = fmaf(av.z, bv.w, acc[2][3]);
            acc[3][0] = fmaf(av.w, bv.x, acc[3][0]);
            acc[3][1] = fmaf(av.w, bv.y, acc[3][1]);
            acc[3][2] = fmaf(av.w, bv.z, acc[3][2]);
            acc[3][3] = fmaf(av.w, bv.w, acc[3][3]);
        }
        __syncthreads();
    }

    const float4 bb = *reinterpret_cast<const float4*>(&bias[col0 + (tx << 2)]);
    #pragma unroll
    for (int i = 0; i < 4; ++i) {
        int row = row0 + (ty << 2) + i;
        int b_ = row >> 11;
        int l  = row & (L_ - 1);
        float4 ob;
        ob.x = acc[i][0] + bb.x;
        ob.y = acc[i][1] + bb.y;
        ob.z = acc[i][2] + bb.z;
        ob.w = acc[i][3] + bb.w;
        *reinterpret_cast<float4*>(&out[(((b_ * NH_) + h) * L_ + l) * HD_ + (tx << 2)]) = ob;
    }
}

// ---------------------------------------------------------------------------
// Kernel 2: sampled scores -> m[b,h,l] = max_s(q.k_samp) - sum_s(q.k_samp)/L
// One wave per (b,h,l).  4 s-values in parallel (16 lanes each, 4 d per lane).
// ---------------------------------------------------------------------------
__global__ __launch_bounds__(256) void sample_m_kernel(
    const float* __restrict__ q, const float* __restrict__ k,
    const int* __restrict__ idx, float* __restrict__ m)
{
    const int wid  = blockIdx.x * 4 + (threadIdx.x >> 6);  // 0..32767
    const int lane = threadIdx.x & 63;
    const int bh = wid >> 11;
    const int l  = wid & (L_ - 1);
    const int grp = lane >> 4, gl = lane & 15;

    const float4 qf = *reinterpret_cast<const float4*>(&q[(bh * L_ + l) * HD_ + (gl << 2)]);

    float mx = -INFINITY, sm = 0.f;
    #pragma unroll
    for (int it = 0; it < 10; ++it) {
        const int s  = it * 4 + grp;
        const int ki = idx[l * SK_ + s];
        const float4 kf = *reinterpret_cast<const float4*>(&k[(bh * L_ + ki) * HD_ + (gl << 2)]);
        float p = qf.x * kf.x + qf.y * kf.y + qf.z * kf.z + qf.w * kf.w;
        p += __shfl_xor(p, 1);
        p += __shfl_xor(p, 2);
        p += __shfl_xor(p, 4);
        p += __shfl_xor(p, 8);
        mx = fmaxf(mx, p);
        sm += p;
    }
    mx = fmaxf(mx, __shfl_xor(mx, 16));
    mx = fmaxf(mx, __shfl_xor(mx, 32));
    sm += __shfl_xor(sm, 16);
    sm += __shfl_xor(sm, 32);
    if (lane == 0) m[bh * L_ + l] = mx - sm * (1.0f / (float)L_);
}

// ---------------------------------------------------------------------------
// Kernel 3: top-40 indices per (b,h) via 40 rounds of argmax (ties -> lower idx)
// ---------------------------------------------------------------------------
__global__ __launch_bounds__(256) void topk_kernel(
    const float* __restrict__ m, int* __restrict__ m_top)
{
    const int bh = blockIdx.x;
    const int t = threadIdx.x;
    __shared__ float vals[L_];
    __shared__ float rv[256];
    __shared__ int   ri[256];

    for (int i = t; i < L_; i += 256) vals[i] = m[bh * L_ + i];
    __syncthreads();

    for (int r = 0; r < NTOP_; ++r) {
        float bv = -INFINITY; int bi = 1 << 30;
        for (int i = t; i < L_; i += 256) {
            float v = vals[i];
            if (v > bv || (v == bv && i < bi)) { bv = v; bi = i; }
        }
        rv[t] = bv; ri[t] = bi;
        __syncthreads();
        for (int s = 128; s > 0; s >>= 1) {
            if (t < s) {
                if (rv[t + s] > rv[t] || (rv[t + s] == rv[t] && ri[t + s] < ri[t])) {
                    rv[t] = rv[t + s]; ri[t] = ri[t + s];
                }
            }
            __syncthreads();
        }
        if (t == 0) { m_top[bh * NTOP_ + r] = ri[0]; vals[ri[0]] = -INFINITY; }
        __syncthreads();
    }
}

// ---------------------------------------------------------------------------
// Kernel 4: vmean[b,h,d] = mean over l of v
// ---------------------------------------------------------------------------
__global__ __launch_bounds__(256) void vmean_kernel(
    const float* __restrict__ v, float* __restrict__ vmean)
{
    const int bh = blockIdx.x;
    const int t = threadIdx.x;
    const int d = t & 63, part = t >> 6;
    float s = 0.f;
    const int l0 = part * (L_ / 4);
    for (int l = l0; l < l0 + (L_ / 4); ++l) s += v[(bh * L_ + l) * HD_ + d];
    __shared__ float red[4][64];
    red[part][d] = s;
    __syncthreads();
    if (part == 0)
        vmean[bh * HD_ + d] = (red[0][d] + red[1][d] + red[2][d] + red[3][d]) * (1.0f / (float)L_);
}

// ---------------------------------------------------------------------------
// Kernel 5: chunked attention partials (flash-style).
// grid (NCH_, NBH_); block 256. CHUNK_=64 keys per block.
// ---------------------------------------------------------------------------
__global__ __launch_bounds__(256) void attn_part_kernel(
    const float* __restrict__ q, const float* __restrict__ k,
    const float* __restrict__ v, const int* __restrict__ m_top,
    float* __restrict__ mx_p, float* __restrict__ sm_p, float* __restrict__ ctx_p)
{
    const int chunk = blockIdx.x;   // 0..31
    const int bh    = blockIdx.y;   // 0..15
    const int t = threadIdx.x;

    __shared__ __align__(16) float  Qs[NTOP_][64];
    __shared__ float4 Ks4[CHUNK_ * 16];          // swizzled 16B columns
    __shared__ __align__(16) float  Vs[CHUNK_][64];
    __shared__ float  S[NTOP_][CHUNK_];

    // load Q rows (gathered by m_top)
    for (int i = t; i < NTOP_ * 16; i += 256) {
        int qi = i >> 4, cc = i & 15;
        int l = m_top[bh * NTOP_ + qi];
        *reinterpret_cast<float4*>(&Qs[qi][cc << 2]) =
            *reinterpret_cast<const float4*>(&q[(bh * L_ + l) * HD_ + (cc << 2)]);
    }
    // load K (swizzled) and V chunk
    const int base = (bh * L_ + chunk * CHUNK_) * HD_;
    for (int i = t; i < CHUNK_ * 16; i += 256) {
        int r = i >> 4, cc = i & 15;
        Ks4[r * 16 + (cc ^ (r & 7))] =
            *reinterpret_cast<const float4*>(&k[base + r * HD_ + (cc << 2)]);
        *reinterpret_cast<float4*>(&Vs[r][cc << 2]) =
            *reinterpret_cast<const float4*>(&v[base + r * HD_ + (cc << 2)]);
    }
    __syncthreads();

    // S[qi][j] = (Qs[qi] . Ks[j]) * 1/8
    for (int o = t; o < NTOP_ * CHUNK_; o += 256) {
        int qi = o >> 6, j = o & (CHUNK_ - 1);
        float acc = 0.f;
        #pragma unroll
        for (int cc = 0; cc < 16; ++cc) {
            float4 kf = Ks4[j * 16 + (cc ^ (j & 7))];
            float4 qf = *reinterpret_cast<const float4*>(&Qs[qi][cc << 2]);
            acc = fmaf(qf.x, kf.x, acc);
            acc = fmaf(qf.y, kf.y, acc);
            acc = fmaf(qf.z, kf.z, acc);
            acc = fmaf(qf.w, kf.w, acc);
        }
        S[qi][j] = acc * 0.125f;
    }
    __syncthreads();

    // per-row partial softmax over the 64 chunk keys (32 lanes per row)
    const int gl = t & 31;
    for (int qi = t >> 5; qi < NTOP_; qi += 8) {
        float v0 = S[qi][gl], v1 = S[qi][gl + 32];
        float mx = fmaxf(v0, v1);
        #pragma unroll
        for (int off = 1; off < 32; off <<= 1) mx = fmaxf(mx, __shfl_xor(mx, off));
        float e0 = __expf(v0 - mx), e1 = __expf(v1 - mx);
        float sm = e0 + e1;
        #pragma unroll
        for (int off = 1; off < 32; off <<= 1) sm += __shfl_xor(sm, off);
        S[qi][gl] = e0; S[qi][gl + 32] = e1;
        if (gl == 0) {
            mx_p[(bh * NCH_ + chunk) * NTOP_ + qi] = mx;
            sm_p[(bh * NCH_ + chunk) * NTOP_ + qi] = sm;
        }
    }
    __syncthreads();

    // ctx partial: ctx_p[qi][d] = sum_j P[qi][j] * Vs[j][d]
    for (int o = t; o < NTOP_ * HD_; o += 256) {
        int qi = o >> 6, d = o & 63;
        float acc = 0.f;
        #pragma unroll 8
        for (int j = 0; j < CHUNK_; ++j) acc = fmaf(S[qi][j], Vs[j][d], acc);
        ctx_p[((bh * NCH_ + chunk) * NTOP_ + qi) * HD_ + d] = acc;
    }
}

// ---------------------------------------------------------------------------
// Kernel 6: online-softmax merge of chunk partials -> ctx_sel
// grid 640 (bh*40+qi), block 64 (d)
// ---------------------------------------------------------------------------
__global__ __launch_bounds__(64) void combine_kernel(
    const float* __restrict__ mx_p, const float* __restrict__ sm_p,
    const float* __restrict__ ctx_p, float* __restrict__ ctx_sel)
{
    const int bq = blockIdx.x;
    const int bh = bq / NTOP_, qi = bq % NTOP_;
    const int d = threadIdx.x;
    float M = -INFINITY;
    for (int c = 0; c < NCH_; ++c)
        M = fmaxf(M, mx_p[(bh * NCH_ + c) * NTOP_ + qi]);
    float den = 0.f, acc = 0.f;
    for (int c = 0; c < NCH_; ++c) {
        float w = __expf(mx_p[(bh * NCH_ + c) * NTOP_ + qi] - M);
        den = fmaf(sm_p[(bh * NCH_ + c) * NTOP_ + qi], w, den);
        acc = fmaf(ctx_p[((bh * NCH_ + c) * NTOP_ + qi) * HD_ + d], w, acc);
    }
    ctx_sel[bq * HD_ + d] = acc / den;
}

// ---------------------------------------------------------------------------
// Kernel 7: base_out[b,j] = vmean_flat[b] . Wo[j,:] + bo[j]
// ---------------------------------------------------------------------------
__global__ __launch_bounds__(256) void base_kernel(
    const float* __restrict__ vmean, const float* __restrict__ Wo,
    const float* __restrict__ bo, float* __restrict__ base_out)
{
    const int b = blockIdx.x;
    const int t = threadIdx.x;
    __shared__ float vm[HID_];
    vm[t] = vmean[b * HID_ + t];
    vm[t + 256] = vmean[b * HID_ + t + 256];
    __syncthreads();
    for (int j = t; j < HID_; j += 256) {
        float acc = bo[j];
        for (int c = 0; c < HID_; c += 4) {
            float4 w = *reinterpret_cast<const float4*>(&Wo[j * HID_ + c]);
            acc = fmaf(vm[c + 0], w.x, acc);
            acc = fmaf(vm[c + 1], w.y, acc);
            acc = fmaf(vm[c + 2], w.z, acc);
            acc = fmaf(vm[c + 3], w.w, acc);
        }
        base_out[b * HID_ + j] = acc;
    }
}

// ---------------------------------------------------------------------------
// Kernel 8: broadcast-fill out with base_out[b]
// ---------------------------------------------------------------------------
__global__ __launch_bounds__(256) void fill_kernel(
    const float* __restrict__ base_out, float* __restrict__ out)
{
    const int i = blockIdx.x * 256 + threadIdx.x;   // float4 index
    if (i >= NROW_ * (HID_ / 4)) return;
    const int j4  = i & 127;
    const int row = i >> 7;
    const int b   = row >> 11;
    reinterpret_cast<float4*>(out)[i] =
        reinterpret_cast<const float4*>(base_out)[b * 128 + j4];
}

// ---------------------------------------------------------------------------
// Kernel 9: delta scatter: out[b, l_sel, :] += (ctx_sel - vmean_h) . Wo_h^T
// grid 640, block 256 (2 j per thread). atomicAdd (same l may be picked by
// multiple heads of the same batch).
// ---------------------------------------------------------------------------
__global__ __launch_bounds__(256) void scatter_kernel(
    const float* __restrict__ ctx_sel, const float* __restrict__ vmean,
    const int* __restrict__ m_top, const float* __restrict__ Wo,
    float* __restrict__ out)
{
    const int bq = blockIdx.x;
    const int bh = bq / NTOP_, qi = bq % NTOP_;
    const int b = bh >> 3, h = bh & 7;
    const int t = threadIdx.x;
    const int l = m_top[bh * NTOP_ + qi];
    __shared__ float delta[HD_];
    if (t < HD_) delta[t] = ctx_sel[bq * HD_ + t] - vmean[bh * HD_ + t];
    __syncthreads();
    for (int j = t; j < HID_; j += 256) {
        float acc = 0.f;
        #pragma unroll
        for (int c = 0; c < HD_; c += 4) {
            float4 w = *reinterpret_cast<const float4*>(&Wo[j * HID_ + h * HD_ + c]);
            acc = fmaf(delta[c + 0], w.x, acc);
            acc = fmaf(delta[c + 1], w.y, acc);
            acc = fmaf(delta[c + 2], w.z, acc);
            acc = fmaf(delta[c + 3], w.w, acc);
        }
        atomicAdd(&out[(b * L_ + l) * HID_ + j], acc);
    }
}

// ---------------------------------------------------------------------------
extern "C" void kernel_launch(void* const* d_in, const int* in_sizes, int n_in,
                              void* d_out, int out_size, void* d_ws, size_t ws_size,
                              hipStream_t stream)
{
    const float* hs  = (const float*)d_in[0];
    const int*   idx = (const int*)  d_in[1];
    const float* Wq  = (const float*)d_in[2];
    const float* bq  = (const float*)d_in[3];
    const float* Wk  = (const float*)d_in[4];
    const float* bk  = (const float*)d_in[5];
    const float* Wv  = (const float*)d_in[6];
    const float* bv  = (const float*)d_in[7];
    const float* Wo  = (const float*)d_in[8];
    const float* bo  = (const float*)d_in[9];
    float* out = (float*)d_out;

    float* ws = (float*)d_ws;
    // workspace layout (float offsets)
    const size_t OFF_Q      = 0;                        // 1,048,576
    const size_t OFF_K      = OFF_Q + (size_t)NBH_ * L_ * HD_;
    const size_t OFF_V      = OFF_K + (size_t)NBH_ * L_ * HD_;
    const size_t OFF_M      = OFF_V + (size_t)NBH_ * L_ * HD_;      // 32768
    const size_t OFF_VMEAN  = OFF_M + (size_t)NBH_ * L_;            // 1024
    const size_t OFF_MXP    = OFF_VMEAN + (size_t)NBH_ * HD_;       // 20480
    const size_t OFF_SMP    = OFF_MXP + (size_t)NBH_ * NCH_ * NTOP_;
    const size_t OFF_CTXP   = OFF_SMP + (size_t)NBH_ * NCH_ * NTOP_; // 1,310,720
    const size_t OFF_CTXSEL = OFF_CTXP + (size_t)NBH_ * NCH_ * NTOP_ * HD_;
    const size_t OFF_BASE   = OFF_CTXSEL + (size_t)NBH_ * NTOP_ * HD_;
    const size_t OFF_TOP    = OFF_BASE + (size_t)B_ * HID_;         // ints

    float* q_      = ws + OFF_Q;
    float* k_      = ws + OFF_K;
    float* v_      = ws + OFF_V;
    float* m_      = ws + OFF_M;
    float* vmean_  = ws + OFF_VMEAN;
    float* mxp_    = ws + OFF_MXP;
    float* smp_    = ws + OFF_SMP;
    float* ctxp_   = ws + OFF_CTXP;
    float* ctxsel_ = ws + OFF_CTXSEL;
    float* base_   = ws + OFF_BASE;
    int*   mtop_   = (int*)(ws + OFF_TOP);

    // 1. QKV projections
    proj_kernel<<<dim3(NROW_ / 64, NH_, 3), 256, 0, stream>>>(
        hs, Wq, bq, Wk, bk, Wv, bv, q_, k_, v_);
    // 2. sampled-score statistic m
    sample_m_kernel<<<(NBH_ * L_) / 4, 256, 0, stream>>>(q_, k_, idx, m_);
    // 3. top-40 per (b,h)
    topk_kernel<<<NBH_, 256, 0, stream>>>(m_, mtop_);
    // 4. v mean
    vmean_kernel<<<NBH_, 256, 0, stream>>>(v_, vmean_);
    // 5. chunked attention partials
    attn_part_kernel<<<dim3(NCH_, NBH_), 256, 0, stream>>>(
        q_, k_, v_, mtop_, mxp_, smp_, ctxp_);
    // 6. merge partials
    combine_kernel<<<NBH_ * NTOP_, 64, 0, stream>>>(mxp_, smp_, ctxp_, ctxsel_);
    // 7. base output row per batch
    base_kernel<<<B_, 256, 0, stream>>>(vmean_, Wo, bo, base_);
    // 8. broadcast fill
    fill_kernel<<<(NROW_ * (HID_ / 4) + 255) / 256, 256, 0, stream>>>(base_, out);
    // 9. delta scatter for the 640 selected rows
    scatter_kernel<<<NBH_ * NTOP_, 256, 0, stream>>>(ctxsel_, vmean_, mtop_, Wo, out);
}

// Round 2
// 315.326 us; speedup vs baseline: 1.1277x; 1.1277x over previous
//
#include <hip/hip_runtime.h>
#include <hip/hip_bf16.h>
#include <math.h>

// Problem constants
#define B_   2
#define L_   2048
#define HID_ 512
#define NH_  8
#define HD_  64
#define SK_  40
#define NTOP_ 40
#define NBH_ (B_ * NH_)        // 16
#define NROW_ (B_ * L_)        // 4096
#define CHUNK_ 64
#define NCH_ (L_ / CHUNK_)     // 32

// ---------------------------------------------------------------------------
// Kernel 1: fused QKV projection.  C[i,j] = sum_k A[i,k] * W[j,k] + bias[j]
// 128x64 tile, BK=32, 256 threads, 8x4 micro-tile. grid 32x8x3 = 768 = 3/CU.
// LDS layout k-major with k-indexed XOR swizzle on the float4 slot:
//   phys_slot = (row>>2) ^ ((k>>2)&7)   -> conflict-free writes AND b128 reads.
// ---------------------------------------------------------------------------
__global__ __launch_bounds__(256, 3) void proj_kernel(
    const float* __restrict__ A,
    const float* __restrict__ Wq, const float* __restrict__ bq,
    const float* __restrict__ Wk, const float* __restrict__ bk,
    const float* __restrict__ Wv, const float* __restrict__ bv,
    float* __restrict__ qo, float* __restrict__ ko, float* __restrict__ vo)
{
    const float* W; const float* bias; float* out;
    if (blockIdx.z == 0)      { W = Wq; bias = bq; out = qo; }
    else if (blockIdx.z == 1) { W = Wk; bias = bk; out = ko; }
    else                      { W = Wv; bias = bv; out = vo; }

    __shared__ __align__(16) float As[32][132];   // [k][swizzled 128 rows], stride 528B
    __shared__ __align__(16) float Bs[32][68];    // [k][swizzled 64 cols],  stride 272B

    const int t    = threadIdx.x;
    const int row0 = blockIdx.x * 128;
    const int h    = blockIdx.y;          // 64-col tile == head
    const int col0 = h * 64;
    const int ry   = t >> 4;              // 0..15 : owns rows ry*8 .. ry*8+7
    const int cx   = t & 15;              // 0..15 : owns cols cx*4 .. cx*4+3

    float acc[8][4] = {};

    const int a_k4 = t & 7;               // float4-group along k
    const int sub  = t >> 3;              // 0..31

    for (int k0 = 0; k0 < HID_; k0 += 32) {
        // stage A: 128 rows x 32 k  (1024 float4, 4 per thread)
        #pragma unroll
        for (int i = 0; i < 4; ++i) {
            const int a_row = i * 32 + sub;           // 0..127
            float4 av = *reinterpret_cast<const float4*>(
                &A[(size_t)(row0 + a_row) * HID_ + k0 + (a_k4 << 2)]);
            const int slot = (a_row >> 2) ^ a_k4;     // 0..31
            float* p = &As[a_k4 << 2][slot * 4 + (a_row & 3)];
            p[0 * 132] = av.x; p[1 * 132] = av.y; p[2 * 132] = av.z; p[3 * 132] = av.w;
        }
        // stage B: 64 cols x 32 k  (512 float4, 2 per thread)
        #pragma unroll
        for (int i = 0; i < 2; ++i) {
            const int b_col = i * 32 + sub;           // 0..63
            float4 wv = *reinterpret_cast<const float4*>(
                &W[(size_t)(col0 + b_col) * HID_ + k0 + (a_k4 << 2)]);
            const int slot = (b_col >> 2) ^ a_k4;     // 0..15
            float* p = &Bs[a_k4 << 2][slot * 4 + (b_col & 3)];
            p[0 * 68] = wv.x; p[1 * 68] = wv.y; p[2 * 68] = wv.z; p[3 * 68] = wv.w;
        }
        __syncthreads();

        #pragma unroll
        for (int kk = 0; kk < 32; ++kk) {
            const int v = kk >> 2;                    // 0..7
            const float4 a0 = *reinterpret_cast<const float4*>(
                &As[kk][((ry * 2)     ^ v) << 2]);    // rows ry*8 .. +3
            const float4 a1 = *reinterpret_cast<const float4*>(
                &As[kk][((ry * 2 + 1) ^ v) << 2]);    // rows ry*8+4 .. +7
            const float4 b0 = *reinterpret_cast<const float4*>(
                &Bs[kk][(cx ^ v) << 2]);              // cols cx*4 .. +3
            const float as[8] = {a0.x, a0.y, a0.z, a0.w, a1.x, a1.y, a1.z, a1.w};
            #pragma unroll
            for (int i = 0; i < 8; ++i) {
                acc[i][0] = fmaf(as[i], b0.x, acc[i][0]);
                acc[i][1] = fmaf(as[i], b0.y, acc[i][1]);
                acc[i][2] = fmaf(as[i], b0.z, acc[i][2]);
                acc[i][3] = fmaf(as[i], b0.w, acc[i][3]);
            }
        }
        __syncthreads();
    }

    const float4 bb = *reinterpret_cast<const float4*>(&bias[col0 + (cx << 2)]);
    #pragma unroll
    for (int i = 0; i < 8; ++i) {
        const int row = row0 + ry * 8 + i;
        const int b_  = row >> 11;
        const int l   = row & (L_ - 1);
        float4 ob;
        ob.x = acc[i][0] + bb.x;
        ob.y = acc[i][1] + bb.y;
        ob.z = acc[i][2] + bb.z;
        ob.w = acc[i][3] + bb.w;
        *reinterpret_cast<float4*>(
            &out[(((size_t)(b_ * NH_ + h)) * L_ + l) * HD_ + (cx << 2)]) = ob;
    }
}

// ---------------------------------------------------------------------------
// Kernel 2: sampled scores -> m[b,h,l] = max_s(q.k_samp) - sum_s(q.k_samp)/L
// One wave per (b,h,l).  4 s-values in parallel (16 lanes each, 4 d per lane).
// ---------------------------------------------------------------------------
__global__ __launch_bounds__(256) void sample_m_kernel(
    const float* __restrict__ q, const float* __restrict__ k,
    const int* __restrict__ idx, float* __restrict__ m)
{
    const int wid  = blockIdx.x * 4 + (threadIdx.x >> 6);  // 0..32767
    const int lane = threadIdx.x & 63;
    const int bh = wid >> 11;
    const int l  = wid & (L_ - 1);
    const int grp = lane >> 4, gl = lane & 15;

    const float4 qf = *reinterpret_cast<const float4*>(&q[(bh * L_ + l) * HD_ + (gl << 2)]);

    float mx = -INFINITY, sm = 0.f;
    #pragma unroll
    for (int it = 0; it < 10; ++it) {
        const int s  = it * 4 + grp;
        const int ki = idx[l * SK_ + s];
        const float4 kf = *reinterpret_cast<const float4*>(&k[(bh * L_ + ki) * HD_ + (gl << 2)]);
        float p = qf.x * kf.x + qf.y * kf.y + qf.z * kf.z + qf.w * kf.w;
        p += __shfl_xor(p, 1);
        p += __shfl_xor(p, 2);
        p += __shfl_xor(p, 4);
        p += __shfl_xor(p, 8);
        mx = fmaxf(mx, p);
        sm += p;
    }
    mx = fmaxf(mx, __shfl_xor(mx, 16));
    mx = fmaxf(mx, __shfl_xor(mx, 32));
    sm += __shfl_xor(sm, 16);
    sm += __shfl_xor(sm, 32);
    if (lane == 0) m[bh * L_ + l] = mx - sm * (1.0f / (float)L_);
}

// ---------------------------------------------------------------------------
// Kernel 3: top-40 per (b,h). 1024 threads; shfl-based argmax, 40 rounds.
// Output order is irrelevant (distinct indices; downstream is permutation-
// invariant), but ties break toward lower index to match jax.lax.top_k.
// ---------------------------------------------------------------------------
__global__ __launch_bounds__(1024) void topk_kernel(
    const float* __restrict__ m, int* __restrict__ m_top)
{
    const int bh = blockIdx.x;
    const int t = threadIdx.x;
    const int lane = t & 63, wv = t >> 6;      // 16 waves
    __shared__ float vals[L_];
    __shared__ float cv[16];
    __shared__ int   ci[16];

    vals[t]        = m[bh * L_ + t];
    vals[t + 1024] = m[bh * L_ + t + 1024];
    __syncthreads();

    for (int r = 0; r < NTOP_; ++r) {
        float v0 = vals[t], v1 = vals[t + 1024];
        float bv; int bi;
        if (v1 > v0) { bv = v1; bi = t + 1024; } else { bv = v0; bi = t; }
        #pragma unroll
        for (int off = 32; off; off >>= 1) {
            float ov = __shfl_xor(bv, off);
            int   oi = __shfl_xor(bi, off);
            if (ov > bv || (ov == bv && oi < bi)) { bv = ov; bi = oi; }
        }
        if (lane == 0) { cv[wv] = bv; ci[wv] = bi; }
        __syncthreads();
        if (t < 16) {
            bv = cv[t]; bi = ci[t];
            #pragma unroll
            for (int off = 8; off; off >>= 1) {
                float ov = __shfl_xor(bv, off);
                int   oi = __shfl_xor(bi, off);
                if (ov > bv || (ov == bv && oi < bi)) { bv = ov; bi = oi; }
            }
            if (t == 0) { m_top[bh * NTOP_ + r] = bi; vals[bi] = -INFINITY; }
        }
        __syncthreads();
    }
}

// ---------------------------------------------------------------------------
// Kernel 4: vmean[b,h,d] = mean over l of v
// ---------------------------------------------------------------------------
__global__ __launch_bounds__(256) void vmean_kernel(
    const float* __restrict__ v, float* __restrict__ vmean)
{
    const int bh = blockIdx.x;
    const int t = threadIdx.x;
    const int d = t & 63, part = t >> 6;
    float s = 0.f;
    const int l0 = part * (L_ / 4);
    for (int l = l0; l < l0 + (L_ / 4); ++l) s += v[(bh * L_ + l) * HD_ + d];
    __shared__ float red[4][64];
    red[part][d] = s;
    __syncthreads();
    if (part == 0)
        vmean[bh * HD_ + d] = (red[0][d] + red[1][d] + red[2][d] + red[3][d]) * (1.0f / (float)L_);
}

// ---------------------------------------------------------------------------
// Kernel 5: chunked attention partials (flash-style).
// grid (NCH_, NBH_); block 256. CHUNK_=64 keys per block.
// ---------------------------------------------------------------------------
__global__ __launch_bounds__(256) void attn_part_kernel(
    const float* __restrict__ q, const float* __restrict__ k,
    const float* __restrict__ v, const int* __restrict__ m_top,
    float* __restrict__ mx_p, float* __restrict__ sm_p, float* __restrict__ ctx_p)
{
    const int chunk = blockIdx.x;   // 0..31
    const int bh    = blockIdx.y;   // 0..15
    const int t = threadIdx.x;

    __shared__ __align__(16) float  Qs[NTOP_][64];
    __shared__ float4 Ks4[CHUNK_ * 16];          // swizzled 16B columns
    __shared__ __align__(16) float  Vs[CHUNK_][64];
    __shared__ float  S[NTOP_][CHUNK_];

    // load Q rows (gathered by m_top)
    for (int i = t; i < NTOP_ * 16; i += 256) {
        int qi = i >> 4, cc = i & 15;
        int l = m_top[bh * NTOP_ + qi];
        *reinterpret_cast<float4*>(&Qs[qi][cc << 2]) =
            *reinterpret_cast<const float4*>(&q[(bh * L_ + l) * HD_ + (cc << 2)]);
    }
    // load K (swizzled) and V chunk
    const int base = (bh * L_ + chunk * CHUNK_) * HD_;
    for (int i = t; i < CHUNK_ * 16; i += 256) {
        int r = i >> 4, cc = i & 15;
        Ks4[r * 16 + (cc ^ (r & 7))] =
            *reinterpret_cast<const float4*>(&k[base + r * HD_ + (cc << 2)]);
        *reinterpret_cast<float4*>(&Vs[r][cc << 2]) =
            *reinterpret_cast<const float4*>(&v[base + r * HD_ + (cc << 2)]);
    }
    __syncthreads();

    // S[qi][j] = (Qs[qi] . Ks[j]) * 1/8
    for (int o = t; o < NTOP_ * CHUNK_; o += 256) {
        int qi = o >> 6, j = o & (CHUNK_ - 1);
        float acc = 0.f;
        #pragma unroll
        for (int cc = 0; cc < 16; ++cc) {
            float4 kf = Ks4[j * 16 + (cc ^ (j & 7))];
            float4 qf = *reinterpret_cast<const float4*>(&Qs[qi][cc << 2]);
            acc = fmaf(qf.x, kf.x, acc);
            acc = fmaf(qf.y, kf.y, acc);
            acc = fmaf(qf.z, kf.z, acc);
            acc = fmaf(qf.w, kf.w, acc);
        }
        S[qi][j] = acc * 0.125f;
    }
    __syncthreads();

    // per-row partial softmax over the 64 chunk keys (32 lanes per row)
    const int gl = t & 31;
    for (int qi = t >> 5; qi < NTOP_; qi += 8) {
        float v0 = S[qi][gl], v1 = S[qi][gl + 32];
        float mx = fmaxf(v0, v1);
        #pragma unroll
        for (int off = 1; off < 32; off <<= 1) mx = fmaxf(mx, __shfl_xor(mx, off));
        float e0 = __expf(v0 - mx), e1 = __expf(v1 - mx);
        float sm = e0 + e1;
        #pragma unroll
        for (int off = 1; off < 32; off <<= 1) sm += __shfl_xor(sm, off);
        S[qi][gl] = e0; S[qi][gl + 32] = e1;
        if (gl == 0) {
            mx_p[(bh * NCH_ + chunk) * NTOP_ + qi] = mx;
            sm_p[(bh * NCH_ + chunk) * NTOP_ + qi] = sm;
        }
    }
    __syncthreads();

    // ctx partial: ctx_p[qi][d] = sum_j P[qi][j] * Vs[j][d]
    for (int o = t; o < NTOP_ * HD_; o += 256) {
        int qi = o >> 6, d = o & 63;
        float acc = 0.f;
        #pragma unroll 8
        for (int j = 0; j < CHUNK_; ++j) acc = fmaf(S[qi][j], Vs[j][d], acc);
        ctx_p[((bh * NCH_ + chunk) * NTOP_ + qi) * HD_ + d] = acc;
    }
}

// ---------------------------------------------------------------------------
// Kernel 6: online-softmax merge of chunk partials -> ctx_sel
// grid 640 (bh*40+qi), block 64 (d)
// ---------------------------------------------------------------------------
__global__ __launch_bounds__(64) void combine_kernel(
    const float* __restrict__ mx_p, const float* __restrict__ sm_p,
    const float* __restrict__ ctx_p, float* __restrict__ ctx_sel)
{
    const int bq = blockIdx.x;
    const int bh = bq / NTOP_, qi = bq % NTOP_;
    const int d = threadIdx.x;
    float M = -INFINITY;
    for (int c = 0; c < NCH_; ++c)
        M = fmaxf(M, mx_p[(bh * NCH_ + c) * NTOP_ + qi]);
    float den = 0.f, acc = 0.f;
    for (int c = 0; c < NCH_; ++c) {
        float w = __expf(mx_p[(bh * NCH_ + c) * NTOP_ + qi] - M);
        den = fmaf(sm_p[(bh * NCH_ + c) * NTOP_ + qi], w, den);
        acc = fmaf(ctx_p[((bh * NCH_ + c) * NTOP_ + qi) * HD_ + d], w, acc);
    }
    ctx_sel[bq * HD_ + d] = acc / den;
}

// ---------------------------------------------------------------------------
// Kernel 7: base_out[b,j] = vmean_flat[b] . Wo[j,:] + bo[j]
// ---------------------------------------------------------------------------
__global__ __launch_bounds__(256) void base_kernel(
    const float* __restrict__ vmean, const float* __restrict__ Wo,
    const float* __restrict__ bo, float* __restrict__ base_out)
{
    const int b = blockIdx.x;
    const int t = threadIdx.x;
    __shared__ float vm[HID_];
    vm[t] = vmean[b * HID_ + t];
    vm[t + 256] = vmean[b * HID_ + t + 256];
    __syncthreads();
    for (int j = t; j < HID_; j += 256) {
        float acc = bo[j];
        for (int c = 0; c < HID_; c += 4) {
            float4 w = *reinterpret_cast<const float4*>(&Wo[j * HID_ + c]);
            acc = fmaf(vm[c + 0], w.x, acc);
            acc = fmaf(vm[c + 1], w.y, acc);
            acc = fmaf(vm[c + 2], w.z, acc);
            acc = fmaf(vm[c + 3], w.w, acc);
        }
        base_out[b * HID_ + j] = acc;
    }
}

// ---------------------------------------------------------------------------
// Kernel 8: broadcast-fill out with base_out[b]
// ---------------------------------------------------------------------------
__global__ __launch_bounds__(256) void fill_kernel(
    const float* __restrict__ base_out, float* __restrict__ out)
{
    const int i = blockIdx.x * 256 + threadIdx.x;   // float4 index
    if (i >= NROW_ * (HID_ / 4)) return;
    const int j4  = i & 127;
    const int row = i >> 7;
    const int b   = row >> 11;
    reinterpret_cast<float4*>(out)[i] =
        reinterpret_cast<const float4*>(base_out)[b * 128 + j4];
}

// ---------------------------------------------------------------------------
// Kernel 9: delta scatter: out[b, l_sel, :] += (ctx_sel - vmean_h) . Wo_h^T
// ---------------------------------------------------------------------------
__global__ __launch_bounds__(256) void scatter_kernel(
    const float* __restrict__ ctx_sel, const float* __restrict__ vmean,
    const int* __restrict__ m_top, const float* __restrict__ Wo,
    float* __restrict__ out)
{
    const int bq = blockIdx.x;
    const int bh = bq / NTOP_, qi = bq % NTOP_;
    const int b = bh >> 3, h = bh & 7;
    const int t = threadIdx.x;
    const int l = m_top[bh * NTOP_ + qi];
    __shared__ float delta[HD_];
    if (t < HD_) delta[t] = ctx_sel[bq * HD_ + t] - vmean[bh * HD_ + t];
    __syncthreads();
    for (int j = t; j < HID_; j += 256) {
        float acc = 0.f;
        #pragma unroll
        for (int c = 0; c < HD_; c += 4) {
            float4 w = *reinterpret_cast<const float4*>(&Wo[j * HID_ + h * HD_ + c]);
            acc = fmaf(delta[c + 0], w.x, acc);
            acc = fmaf(delta[c + 1], w.y, acc);
            acc = fmaf(delta[c + 2], w.z, acc);
            acc = fmaf(delta[c + 3], w.w, acc);
        }
        atomicAdd(&out[(b * L_ + l) * HID_ + j], acc);
    }
}

// ---------------------------------------------------------------------------
extern "C" void kernel_launch(void* const* d_in, const int* in_sizes, int n_in,
                              void* d_out, int out_size, void* d_ws, size_t ws_size,
                              hipStream_t stream)
{
    const float* hs  = (const float*)d_in[0];
    const int*   idx = (const int*)  d_in[1];
    const float* Wq  = (const float*)d_in[2];
    const float* bq  = (const float*)d_in[3];
    const float* Wk  = (const float*)d_in[4];
    const float* bk  = (const float*)d_in[5];
    const float* Wv  = (const float*)d_in[6];
    const float* bv  = (const float*)d_in[7];
    const float* Wo  = (const float*)d_in[8];
    const float* bo  = (const float*)d_in[9];
    float* out = (float*)d_out;

    float* ws = (float*)d_ws;
    const size_t OFF_Q      = 0;
    const size_t OFF_K      = OFF_Q + (size_t)NBH_ * L_ * HD_;
    const size_t OFF_V      = OFF_K + (size_t)NBH_ * L_ * HD_;
    const size_t OFF_M      = OFF_V + (size_t)NBH_ * L_ * HD_;
    const size_t OFF_VMEAN  = OFF_M + (size_t)NBH_ * L_;
    const size_t OFF_MXP    = OFF_VMEAN + (size_t)NBH_ * HD_;
    const size_t OFF_SMP    = OFF_MXP + (size_t)NBH_ * NCH_ * NTOP_;
    const size_t OFF_CTXP   = OFF_SMP + (size_t)NBH_ * NCH_ * NTOP_;
    const size_t OFF_CTXSEL = OFF_CTXP + (size_t)NBH_ * NCH_ * NTOP_ * HD_;
    const size_t OFF_BASE   = OFF_CTXSEL + (size_t)NBH_ * NTOP_ * HD_;
    const size_t OFF_TOP    = OFF_BASE + (size_t)B_ * HID_;

    float* q_      = ws + OFF_Q;
    float* k_      = ws + OFF_K;
    float* v_      = ws + OFF_V;
    float* m_      = ws + OFF_M;
    float* vmean_  = ws + OFF_VMEAN;
    float* mxp_    = ws + OFF_MXP;
    float* smp_    = ws + OFF_SMP;
    float* ctxp_   = ws + OFF_CTXP;
    float* ctxsel_ = ws + OFF_CTXSEL;
    float* base_   = ws + OFF_BASE;
    int*   mtop_   = (int*)(ws + OFF_TOP);

    proj_kernel<<<dim3(NROW_ / 128, NH_, 3), 256, 0, stream>>>(
        hs, Wq, bq, Wk, bk, Wv, bv, q_, k_, v_);
    sample_m_kernel<<<(NBH_ * L_) / 4, 256, 0, stream>>>(q_, k_, idx, m_);
    topk_kernel<<<NBH_, 1024, 0, stream>>>(m_, mtop_);
    vmean_kernel<<<NBH_, 256, 0, stream>>>(v_, vmean_);
    attn_part_kernel<<<dim3(NCH_, NBH_), 256, 0, stream>>>(
        q_, k_, v_, mtop_, mxp_, smp_, ctxp_);
    combine_kernel<<<NBH_ * NTOP_, 64, 0, stream>>>(mxp_, smp_, ctxp_, ctxsel_);
    base_kernel<<<B_, 256, 0, stream>>>(vmean_, Wo, bo, base_);
    fill_kernel<<<(NROW_ * (HID_ / 4) + 255) / 256, 256, 0, stream>>>(base_, out);
    scatter_kernel<<<NBH_ * NTOP_, 256, 0, stream>>>(ctxsel_, vmean_, mtop_, Wo, out);
}

// Round 4
// 253.245 us; speedup vs baseline: 1.4041x; 1.2451x over previous
//
#include <hip/hip_runtime.h>
#include <hip/hip_bf16.h>
#include <math.h>

// Problem constants
#define B_   2
#define L_   2048
#define HID_ 512
#define NH_  8
#define HD_  64
#define SK_  40
#define NTOP_ 40
#define NBH_ (B_ * NH_)        // 16
#define NROW_ (B_ * L_)        // 4096
#define CHUNK_ 64
#define NCH_ (L_ / CHUNK_)     // 32

// ---------------------------------------------------------------------------
// Kernel 0: zero vmean accumulator (ws is poisoned 0xAA each call)
// ---------------------------------------------------------------------------
__global__ __launch_bounds__(256) void zero_kernel(float* __restrict__ vmean)
{
    const int t = threadIdx.x;
    #pragma unroll
    for (int i = 0; i < 4; ++i) vmean[t + i * 256] = 0.f;
}

// ---------------------------------------------------------------------------
// Kernel 1: fused QKV projection, register-prefetch pipelined.
// C[i,j] = sum_k A[i,k]*W[j,k] + bias[j].  128x64 tile, BK=32, 8x4 micro.
// k-indexed XOR swizzle on float4 slot -> conflict-free writes + b128 reads.
// z==2 (V) additionally accumulates vmean via atomics.
// ---------------------------------------------------------------------------
__global__ __launch_bounds__(256, 3) void proj_kernel(
    const float* __restrict__ A,
    const float* __restrict__ Wq, const float* __restrict__ bq,
    const float* __restrict__ Wk, const float* __restrict__ bk,
    const float* __restrict__ Wv, const float* __restrict__ bv,
    float* __restrict__ qo, float* __restrict__ ko, float* __restrict__ vo,
    float* __restrict__ vmean)
{
    const float* W; const float* bias; float* out;
    if (blockIdx.z == 0)      { W = Wq; bias = bq; out = qo; }
    else if (blockIdx.z == 1) { W = Wk; bias = bk; out = ko; }
    else                      { W = Wv; bias = bv; out = vo; }

    __shared__ __align__(16) float As[32][132];
    __shared__ __align__(16) float Bs[32][68];
    __shared__ float red[16][64];              // vmean partial reduce (z==2)

    const int t    = threadIdx.x;
    const int row0 = blockIdx.x * 128;
    const int h    = blockIdx.y;
    const int col0 = h * 64;
    const int ry   = t >> 4;              // 0..15 : rows ry*8 .. +7
    const int cx   = t & 15;              // 0..15 : cols cx*4 .. +3
    const int a_k4 = t & 7;
    const int sub  = t >> 3;              // 0..31

    float acc[8][4] = {};
    float4 pa[4], pb[2];

    // prologue: load k-tile 0 into registers
    #pragma unroll
    for (int i = 0; i < 4; ++i)
        pa[i] = *reinterpret_cast<const float4*>(
            &A[(size_t)(row0 + i * 32 + sub) * HID_ + (a_k4 << 2)]);
    #pragma unroll
    for (int i = 0; i < 2; ++i)
        pb[i] = *reinterpret_cast<const float4*>(
            &W[(size_t)(col0 + i * 32 + sub) * HID_ + (a_k4 << 2)]);

    for (int ks = 0; ks < 16; ++ks) {
        // store prefetched regs -> LDS (swizzled)
        #pragma unroll
        for (int i = 0; i < 4; ++i) {
            const int a_row = i * 32 + sub;
            const int slot = (a_row >> 2) ^ a_k4;
            float* p = &As[a_k4 << 2][slot * 4 + (a_row & 3)];
            p[0 * 132] = pa[i].x; p[1 * 132] = pa[i].y;
            p[2 * 132] = pa[i].z; p[3 * 132] = pa[i].w;
        }
        #pragma unroll
        for (int i = 0; i < 2; ++i) {
            const int b_col = i * 32 + sub;
            const int slot = (b_col >> 2) ^ a_k4;
            float* p = &Bs[a_k4 << 2][slot * 4 + (b_col & 3)];
            p[0 * 68] = pb[i].x; p[1 * 68] = pb[i].y;
            p[2 * 68] = pb[i].z; p[3 * 68] = pb[i].w;
        }
        __syncthreads();

        // issue next tile's global loads; vmcnt waits land at next store phase
        if (ks < 15) {
            const int k0 = (ks + 1) * 32;
            #pragma unroll
            for (int i = 0; i < 4; ++i)
                pa[i] = *reinterpret_cast<const float4*>(
                    &A[(size_t)(row0 + i * 32 + sub) * HID_ + k0 + (a_k4 << 2)]);
            #pragma unroll
            for (int i = 0; i < 2; ++i)
                pb[i] = *reinterpret_cast<const float4*>(
                    &W[(size_t)(col0 + i * 32 + sub) * HID_ + k0 + (a_k4 << 2)]);
        }

        #pragma unroll
        for (int kk = 0; kk < 32; ++kk) {
            const int v = kk >> 2;
            const float4 a0 = *reinterpret_cast<const float4*>(
                &As[kk][((ry * 2)     ^ v) << 2]);
            const float4 a1 = *reinterpret_cast<const float4*>(
                &As[kk][((ry * 2 + 1) ^ v) << 2]);
            const float4 b0 = *reinterpret_cast<const float4*>(
                &Bs[kk][(cx ^ v) << 2]);
            const float as[8] = {a0.x, a0.y, a0.z, a0.w, a1.x, a1.y, a1.z, a1.w};
            #pragma unroll
            for (int i = 0; i < 8; ++i) {
                acc[i][0] = fmaf(as[i], b0.x, acc[i][0]);
                acc[i][1] = fmaf(as[i], b0.y, acc[i][1]);
                acc[i][2] = fmaf(as[i], b0.z, acc[i][2]);
                acc[i][3] = fmaf(as[i], b0.w, acc[i][3]);
            }
        }
        __syncthreads();
    }

    const float4 bb = *reinterpret_cast<const float4*>(&bias[col0 + (cx << 2)]);
    const int b_ = row0 >> 11;            // 128-row tile lies within one batch
    #pragma unroll
    for (int i = 0; i < 8; ++i) {
        const int row = row0 + ry * 8 + i;
        const int l   = row & (L_ - 1);
        float4 ob;
        ob.x = acc[i][0] + bb.x;
        ob.y = acc[i][1] + bb.y;
        ob.z = acc[i][2] + bb.z;
        ob.w = acc[i][3] + bb.w;
        *reinterpret_cast<float4*>(
            &out[(((size_t)(b_ * NH_ + h)) * L_ + l) * HD_ + (cx << 2)]) = ob;
    }

    // fused vmean partial (V blocks only)
    if (blockIdx.z == 2) {
        #pragma unroll
        for (int j = 0; j < 4; ++j) {
            float s_ = 0.f;
            #pragma unroll
            for (int i = 0; i < 8; ++i) s_ += acc[i][j];
            const float bj = (j == 0) ? bb.x : (j == 1) ? bb.y : (j == 2) ? bb.z : bb.w;
            red[ry][(cx << 2) + j] = s_ + 8.f * bj;
        }
        __syncthreads();
        if (t < 64) {
            float s_ = 0.f;
            #pragma unroll
            for (int r = 0; r < 16; ++r) s_ += red[r][t];
            atomicAdd(&vmean[(b_ * NH_ + h) * HD_ + t], s_ * (1.0f / (float)L_));
        }
    }
}

// ---------------------------------------------------------------------------
// Kernel 2: sampled scores -> m[b,h,l] = max_s(q.k_samp) - sum_s(q.k_samp)/L
// ---------------------------------------------------------------------------
__global__ __launch_bounds__(256) void sample_m_kernel(
    const float* __restrict__ q, const float* __restrict__ k,
    const int* __restrict__ idx, float* __restrict__ m)
{
    const int wid  = blockIdx.x * 4 + (threadIdx.x >> 6);
    const int lane = threadIdx.x & 63;
    const int bh = wid >> 11;
    const int l  = wid & (L_ - 1);
    const int grp = lane >> 4, gl = lane & 15;

    const float4 qf = *reinterpret_cast<const float4*>(&q[(bh * L_ + l) * HD_ + (gl << 2)]);

    float mx = -INFINITY, sm = 0.f;
    #pragma unroll
    for (int it = 0; it < 10; ++it) {
        const int s  = it * 4 + grp;
        const int ki = idx[l * SK_ + s];
        const float4 kf = *reinterpret_cast<const float4*>(&k[(bh * L_ + ki) * HD_ + (gl << 2)]);
        float p = qf.x * kf.x + qf.y * kf.y + qf.z * kf.z + qf.w * kf.w;
        p += __shfl_xor(p, 1);
        p += __shfl_xor(p, 2);
        p += __shfl_xor(p, 4);
        p += __shfl_xor(p, 8);
        mx = fmaxf(mx, p);
        sm += p;
    }
    mx = fmaxf(mx, __shfl_xor(mx, 16));
    mx = fmaxf(mx, __shfl_xor(mx, 32));
    sm += __shfl_xor(sm, 16);
    sm += __shfl_xor(sm, 32);
    if (lane == 0) m[bh * L_ + l] = mx - sm * (1.0f / (float)L_);
}

// ---------------------------------------------------------------------------
// Kernel 3: top-40 per (b,h) via 4-round byte-radix select (exact, ties ->
// lowest index, output order arbitrary — downstream is permutation-invariant).
// ---------------------------------------------------------------------------
__global__ __launch_bounds__(256) void topk_kernel(
    const float* __restrict__ m, int* __restrict__ m_top)
{
    const int bh = blockIdx.x;
    const int t  = threadIdx.x;
    __shared__ unsigned uv[L_];
    __shared__ int hist[256];
    __shared__ int sfx[257];
    __shared__ int s_selByte, s_cntG, s_outcnt, s_tieCnt;
    __shared__ int tie[256];

    for (int i = t; i < L_; i += 256) {
        unsigned x = __float_as_uint(m[bh * L_ + i]);
        uv[i] = (x & 0x80000000u) ? ~x : (x | 0x80000000u);
    }
    if (t == 0) { s_outcnt = 0; s_tieCnt = 0; }
    __syncthreads();

    unsigned prefHigh = 0;
    int cntG = 0;
    for (int shift = 24; shift >= 0; shift -= 8) {
        hist[t] = 0;
        __syncthreads();
        for (int i = t; i < L_; i += 256) {
            unsigned x = uv[i];
            bool inCls = (shift == 24) || ((x >> (shift + 8)) == prefHigh);
            if (inCls) atomicAdd(&hist[(x >> shift) & 255], 1);
        }
        __syncthreads();
        if (t < 64) {                      // wave 0: suffix scan of 256 bins
            int h0 = hist[4 * t], h1 = hist[4 * t + 1];
            int h2 = hist[4 * t + 2], h3 = hist[4 * t + 3];
            int s3 = h3, s2 = h2 + s3, s1 = h1 + s2, s0 = h0 + s1;
            int sum = s0;
            #pragma unroll
            for (int off = 1; off < 64; off <<= 1) {
                int v = __shfl_down(sum, off);
                if (t + off < 64) sum += v;
            }
            const int after = sum - s0;    // suffix over lanes > t
            sfx[4 * t]     = s0 + after;
            sfx[4 * t + 1] = s1 + after;
            sfx[4 * t + 2] = s2 + after;
            sfx[4 * t + 3] = s3 + after;
            if (t == 0) sfx[256] = 0;
        }
        __syncthreads();
        {
            const int sAt = sfx[t], sNext = sfx[t + 1];
            if (cntG + sAt >= NTOP_ && cntG + sNext < NTOP_) {
                s_selByte = t;
                s_cntG = cntG + sNext;
            }
        }
        __syncthreads();
        prefHigh = (prefHigh << 8) | (unsigned)s_selByte;
        cntG = s_cntG;
        __syncthreads();
    }
    const unsigned T = prefHigh;

    for (int i = t; i < L_; i += 256) {
        const unsigned x = uv[i];
        if (x > T) {
            const int p = atomicAdd(&s_outcnt, 1);
            m_top[bh * NTOP_ + p] = i;
        } else if (x == T) {
            const int p = atomicAdd(&s_tieCnt, 1);
            if (p < 256) tie[p] = i;
        }
    }
    __syncthreads();
    if (t == 0) {
        const int rem = NTOP_ - s_outcnt;
        const int n = s_tieCnt;
        if (n > 256) {                     // pathological tie flood: serial
            int w = s_outcnt;
            for (int i = 0; i < L_ && w < NTOP_; ++i)
                if (uv[i] == T) m_top[bh * NTOP_ + w++] = i;
        } else {
            for (int r = 0; r < rem; ++r) {
                int best = 1 << 30, bj = -1;
                for (int j2 = 0; j2 < n; ++j2)
                    if (tie[j2] < best) { best = tie[j2]; bj = j2; }
                tie[bj] = 1 << 30;
                m_top[bh * NTOP_ + s_outcnt + r] = best;
            }
        }
    }
}

// ---------------------------------------------------------------------------
// Kernel 5: chunked attention partials (flash-style).
// ---------------------------------------------------------------------------
__global__ __launch_bounds__(256) void attn_part_kernel(
    const float* __restrict__ q, const float* __restrict__ k,
    const float* __restrict__ v, const int* __restrict__ m_top,
    float* __restrict__ mx_p, float* __restrict__ sm_p, float* __restrict__ ctx_p)
{
    const int chunk = blockIdx.x;
    const int bh    = blockIdx.y;
    const int t = threadIdx.x;

    __shared__ __align__(16) float  Qs[NTOP_][64];
    __shared__ float4 Ks4[CHUNK_ * 16];
    __shared__ __align__(16) float  Vs[CHUNK_][64];
    __shared__ float  S[NTOP_][CHUNK_];

    for (int i = t; i < NTOP_ * 16; i += 256) {
        int qi = i >> 4, cc = i & 15;
        int l = m_top[bh * NTOP_ + qi];
        *reinterpret_cast<float4*>(&Qs[qi][cc << 2]) =
            *reinterpret_cast<const float4*>(&q[(bh * L_ + l) * HD_ + (cc << 2)]);
    }
    const int base = (bh * L_ + chunk * CHUNK_) * HD_;
    for (int i = t; i < CHUNK_ * 16; i += 256) {
        int r = i >> 4, cc = i & 15;
        Ks4[r * 16 + (cc ^ (r & 7))] =
            *reinterpret_cast<const float4*>(&k[base + r * HD_ + (cc << 2)]);
        *reinterpret_cast<float4*>(&Vs[r][cc << 2]) =
            *reinterpret_cast<const float4*>(&v[base + r * HD_ + (cc << 2)]);
    }
    __syncthreads();

    for (int o = t; o < NTOP_ * CHUNK_; o += 256) {
        int qi = o >> 6, j = o & (CHUNK_ - 1);
        float acc = 0.f;
        #pragma unroll
        for (int cc = 0; cc < 16; ++cc) {
            float4 kf = Ks4[j * 16 + (cc ^ (j & 7))];
            float4 qf = *reinterpret_cast<const float4*>(&Qs[qi][cc << 2]);
            acc = fmaf(qf.x, kf.x, acc);
            acc = fmaf(qf.y, kf.y, acc);
            acc = fmaf(qf.z, kf.z, acc);
            acc = fmaf(qf.w, kf.w, acc);
        }
        S[qi][j] = acc * 0.125f;
    }
    __syncthreads();

    const int gl = t & 31;
    for (int qi = t >> 5; qi < NTOP_; qi += 8) {
        float v0 = S[qi][gl], v1 = S[qi][gl + 32];
        float mx = fmaxf(v0, v1);
        #pragma unroll
        for (int off = 1; off < 32; off <<= 1) mx = fmaxf(mx, __shfl_xor(mx, off));
        float e0 = __expf(v0 - mx), e1 = __expf(v1 - mx);
        float sm = e0 + e1;
        #pragma unroll
        for (int off = 1; off < 32; off <<= 1) sm += __shfl_xor(sm, off);
        S[qi][gl] = e0; S[qi][gl + 32] = e1;
        if (gl == 0) {
            mx_p[(bh * NCH_ + chunk) * NTOP_ + qi] = mx;
            sm_p[(bh * NCH_ + chunk) * NTOP_ + qi] = sm;
        }
    }
    __syncthreads();

    for (int o = t; o < NTOP_ * HD_; o += 256) {
        int qi = o >> 6, d = o & 63;
        float acc = 0.f;
        #pragma unroll 8
        for (int j = 0; j < CHUNK_; ++j) acc = fmaf(S[qi][j], Vs[j][d], acc);
        ctx_p[((bh * NCH_ + chunk) * NTOP_ + qi) * HD_ + d] = acc;
    }
}

// ---------------------------------------------------------------------------
// Kernel 6: fused combine + delta scatter.
// grid 640 (bh*40+qi), block 256 = 4 chunk-groups x 64 d.
// ---------------------------------------------------------------------------
__global__ __launch_bounds__(256) void combscat_kernel(
    const float* __restrict__ mx_p, const float* __restrict__ sm_p,
    const float* __restrict__ ctx_p, const float* __restrict__ vmean,
    const int* __restrict__ m_top, const float* __restrict__ Wo,
    float* __restrict__ out)
{
    const int bq = blockIdx.x;
    const int bh = bq / NTOP_, qi = bq % NTOP_;
    const int b = bh >> 3, h = bh & 7;
    const int t = threadIdx.x;
    const int g = t >> 6, d = t & 63;

    __shared__ float Mg[4], Dg[4];
    __shared__ float Ag[4][64];
    __shared__ float delta[64];

    float mxs[8];
    #pragma unroll
    for (int c8 = 0; c8 < 8; ++c8)
        mxs[c8] = mx_p[(bh * NCH_ + g * 8 + c8) * NTOP_ + qi];
    float M = mxs[0];
    #pragma unroll
    for (int c8 = 1; c8 < 8; ++c8) M = fmaxf(M, mxs[c8]);
    float den = 0.f, acc = 0.f;
    #pragma unroll
    for (int c8 = 0; c8 < 8; ++c8) {
        const int c = g * 8 + c8;
        const float w = __expf(mxs[c8] - M);
        den = fmaf(sm_p[(bh * NCH_ + c) * NTOP_ + qi], w, den);
        acc = fmaf(ctx_p[((bh * NCH_ + c) * NTOP_ + qi) * HD_ + d], w, acc);
    }
    if (d == 0) { Mg[g] = M; Dg[g] = den; }
    Ag[g][d] = acc;
    __syncthreads();
    if (t < 64) {
        const float MM = fmaxf(fmaxf(Mg[0], Mg[1]), fmaxf(Mg[2], Mg[3]));
        float dd = 0.f, aa = 0.f;
        #pragma unroll
        for (int gg = 0; gg < 4; ++gg) {
            const float w = __expf(Mg[gg] - MM);
            dd = fmaf(Dg[gg], w, dd);
            aa = fmaf(Ag[gg][t], w, aa);
        }
        delta[t] = aa / dd - vmean[bh * HD_ + t];
    }
    __syncthreads();
    const int l = m_top[bh * NTOP_ + qi];
    for (int j = t; j < HID_; j += 256) {
        float a2 = 0.f;
        #pragma unroll
        for (int c = 0; c < HD_; c += 4) {
            float4 w = *reinterpret_cast<const float4*>(&Wo[(size_t)j * HID_ + h * HD_ + c]);
            a2 = fmaf(delta[c + 0], w.x, a2);
            a2 = fmaf(delta[c + 1], w.y, a2);
            a2 = fmaf(delta[c + 2], w.z, a2);
            a2 = fmaf(delta[c + 3], w.w, a2);
        }
        atomicAdd(&out[((size_t)(b * L_ + l)) * HID_ + j], a2);
    }
}

// ---------------------------------------------------------------------------
// Kernel 7: base_out[b,j] = vmean_flat[b] . Wo[j,:] + bo[j]
// ---------------------------------------------------------------------------
__global__ __launch_bounds__(256) void base_kernel(
    const float* __restrict__ vmean, const float* __restrict__ Wo,
    const float* __restrict__ bo, float* __restrict__ base_out)
{
    const int b = blockIdx.x;
    const int t = threadIdx.x;
    __shared__ float vm[HID_];
    vm[t] = vmean[b * HID_ + t];
    vm[t + 256] = vmean[b * HID_ + t + 256];
    __syncthreads();
    for (int j = t; j < HID_; j += 256) {
        float acc = bo[j];
        for (int c = 0; c < HID_; c += 4) {
            float4 w = *reinterpret_cast<const float4*>(&Wo[j * HID_ + c]);
            acc = fmaf(vm[c + 0], w.x, acc);
            acc = fmaf(vm[c + 1], w.y, acc);
            acc = fmaf(vm[c + 2], w.z, acc);
            acc = fmaf(vm[c + 3], w.w, acc);
        }
        base_out[b * HID_ + j] = acc;
    }
}

// ---------------------------------------------------------------------------
// Kernel 8: broadcast-fill out with base_out[b]
// ---------------------------------------------------------------------------
__global__ __launch_bounds__(256) void fill_kernel(
    const float* __restrict__ base_out, float* __restrict__ out)
{
    const int i = blockIdx.x * 256 + threadIdx.x;
    if (i >= NROW_ * (HID_ / 4)) return;
    const int j4  = i & 127;
    const int row = i >> 7;
    const int b   = row >> 11;
    reinterpret_cast<float4*>(out)[i] =
        reinterpret_cast<const float4*>(base_out)[b * 128 + j4];
}

// ---------------------------------------------------------------------------
extern "C" void kernel_launch(void* const* d_in, const int* in_sizes, int n_in,
                              void* d_out, int out_size, void* d_ws, size_t ws_size,
                              hipStream_t stream)
{
    const float* hs  = (const float*)d_in[0];
    const int*   idx = (const int*)  d_in[1];
    const float* Wq  = (const float*)d_in[2];
    const float* bq  = (const float*)d_in[3];
    const float* Wk  = (const float*)d_in[4];
    const float* bk  = (const float*)d_in[5];
    const float* Wv  = (const float*)d_in[6];
    const float* bv  = (const float*)d_in[7];
    const float* Wo  = (const float*)d_in[8];
    const float* bo  = (const float*)d_in[9];
    float* out = (float*)d_out;

    float* ws = (float*)d_ws;
    const size_t OFF_Q      = 0;
    const size_t OFF_K      = OFF_Q + (size_t)NBH_ * L_ * HD_;
    const size_t OFF_V      = OFF_K + (size_t)NBH_ * L_ * HD_;
    const size_t OFF_M      = OFF_V + (size_t)NBH_ * L_ * HD_;
    const size_t OFF_VMEAN  = OFF_M + (size_t)NBH_ * L_;
    const size_t OFF_MXP    = OFF_VMEAN + (size_t)NBH_ * HD_;
    const size_t OFF_SMP    = OFF_MXP + (size_t)NBH_ * NCH_ * NTOP_;
    const size_t OFF_CTXP   = OFF_SMP + (size_t)NBH_ * NCH_ * NTOP_;
    const size_t OFF_BASE   = OFF_CTXP + (size_t)NBH_ * NCH_ * NTOP_ * HD_;
    const size_t OFF_TOP    = OFF_BASE + (size_t)B_ * HID_;

    float* q_      = ws + OFF_Q;
    float* k_      = ws + OFF_K;
    float* v_      = ws + OFF_V;
    float* m_      = ws + OFF_M;
    float* vmean_  = ws + OFF_VMEAN;
    float* mxp_    = ws + OFF_MXP;
    float* smp_    = ws + OFF_SMP;
    float* ctxp_   = ws + OFF_CTXP;
    float* base_   = ws + OFF_BASE;
    int*   mtop_   = (int*)(ws + OFF_TOP);

    zero_kernel<<<1, 256, 0, stream>>>(vmean_);
    proj_kernel<<<dim3(NROW_ / 128, NH_, 3), 256, 0, stream>>>(
        hs, Wq, bq, Wk, bk, Wv, bv, q_, k_, v_, vmean_);
    sample_m_kernel<<<(NBH_ * L_) / 4, 256, 0, stream>>>(q_, k_, idx, m_);
    topk_kernel<<<NBH_, 256, 0, stream>>>(m_, mtop_);
    attn_part_kernel<<<dim3(NCH_, NBH_), 256, 0, stream>>>(
        q_, k_, v_, mtop_, mxp_, smp_, ctxp_);
    base_kernel<<<B_, 256, 0, stream>>>(vmean_, Wo, bo, base_);
    fill_kernel<<<(NROW_ * (HID_ / 4) + 255) / 256, 256, 0, stream>>>(base_, out);
    combscat_kernel<<<NBH_ * NTOP_, 256, 0, stream>>>(
        mxp_, smp_, ctxp_, vmean_, mtop_, Wo, out);
}